// Round 14
// baseline (297.291 us; speedup 1.0000x reference)
//
#include <hip/hip_runtime.h>

#define B_    4
#define S_    1024
#define H_    32
#define HKV_  8
#define D_    128
#define NTOT  (B_*S_)
#define QTB_  128      // q rows per block (8 waves x 16 rows)
#define KT_   32

// 1/sqrt(128) * log2(e): scores computed directly in log2 domain
#define QSCALE_ (0.08838834764831845f * 1.4426950408889634f)
#define LN2_    0.6931471805599453f
#define DEFER_  11.5f   // defer-max threshold in log2 units (~e^8)

typedef __attribute__((ext_vector_type(8))) short bf16x8;
typedef __attribute__((ext_vector_type(4))) short bf16x4;
typedef __attribute__((ext_vector_type(4))) float f32x4;
typedef __attribute__((ext_vector_type(4))) int   int4v;

__device__ __forceinline__ unsigned short f2bf(float f) {
    unsigned int u = __float_as_uint(f);
    u += 0x7FFFu + ((u >> 16) & 1u);   // round-to-nearest-even
    return (unsigned short)(u >> 16);
}
__device__ __forceinline__ unsigned int pack2bf(float a, float b) {
    return (unsigned int)f2bf(a) | ((unsigned int)f2bf(b) << 16);
}
__device__ __forceinline__ unsigned int cvtpk_bf16(float a, float b) {
    unsigned int r;
    asm("v_cvt_pk_bf16_f32 %0, %1, %2" : "=v"(r) : "v"(a), "v"(b));
    return r;   // lo = bf16(a), hi = bf16(b), RNE
}
__device__ __forceinline__ float exp2_(float x) {
    float r; asm("v_exp_f32 %0, %1" : "=v"(r) : "v"(x)); return r;
}
__device__ __forceinline__ float max3_(float a, float b, float c) {
    float r; asm("v_max3_f32 %0, %1, %2, %3" : "=v"(r) : "v"(a), "v"(b), "v"(c)); return r;
}
// async global->LDS DMA, 16B/lane; lds base must be wave-uniform, lane l lands at base + l*16
__device__ __forceinline__ void lds_dma16(const void* g, void* l) {
    __builtin_amdgcn_global_load_lds(
        (const __attribute__((address_space(1))) unsigned int*)g,
        (__attribute__((address_space(3))) unsigned int*)l, 16, 0, 0);
}

// ---------------- fused prep ----------------
// blocks [0,512):        V cast+transpose -> vt (bank-swizzle BAKED)
// blocks [512,512+4096): per-token RoPE: sincos ONCE into LDS, then q-rope (32 h,
//                        pre-scaled, -> first 256B of o_out slots) and k-rope
//                        (8 hk, granule-swizzle BAKED -> kr).
#define VT_BLOCKS (B_ * HKV_ * (S_ / 64))   // 512
__global__ void prep_kernel(const float* __restrict__ v,
                            unsigned short* __restrict__ vt,
                            const float* __restrict__ k,
                            const float* __restrict__ theta,
                            unsigned short* __restrict__ kr,
                            const float* __restrict__ q,
                            float* __restrict__ o_out) {
    __shared__ unsigned int T[64][64];      // vt branch: [s][d-pair] swizzled staging
    __shared__ float cs_[64], sn_[64];      // rope branch: per-token sincos table
    const int tid = threadIdx.x;

    if (blockIdx.x < VT_BLOCKS) {
        int blk = blockIdx.x;               // B*HKV*(S/64) = 512 blocks
        int s0  = (blk & (S_/64 - 1)) * 64;
        int hk  = (blk >> 4) & (HKV_ - 1);
        int b   = blk >> 7;

#pragma unroll
        for (int i = 0; i < 8; ++i) {
            int u  = tid + 256 * i;
            int s  = u >> 5;             // 0..63
            int G  = u & 31;             // d granule (4 floats)
            float4 val = *(const float4*)(v + (((size_t)(b * S_ + s0 + s)) * HKV_ + hk) * D_ + G * 4);
            unsigned int* p = &T[s][(G ^ (s & 31)) << 1];
            p[0] = pack2bf(val.x, val.y);
            p[1] = pack2bf(val.z, val.w);
        }
        __syncthreads();
#pragma unroll
        for (int i = 0; i < 4; ++i) {
            int u = tid + 256 * i;
            int d = u >> 3;              // 0..127
            int g = u & 7;               // s granule of 8 keys within the 64-key block
            int G = d >> 2;
            int half = (d >> 1) & 1;
            int hi   = (d & 1) * 16;
            const int hswap = ((d >> 1) & 1) * 4;      // swap 8B halves iff s&1
            alignas(16) unsigned short tmp[8];
#pragma unroll
            for (int j = 0; j < 8; ++j) {
                int s = g * 8 + j;
                unsigned int w = T[s][(((G ^ (s & 31)) << 1)) + half];
                tmp[j ^ hswap] = (unsigned short)(w >> hi);
            }
            const int pos = (g >> 2) * 32 + (((g & 3) ^ ((d >> 2) & 3)) * 8);
            *(int4v*)(vt + (((size_t)(b * HKV_ + hk)) * D_ + d) * S_ + s0 + pos) = *(const int4v*)tmp;
        }
    } else {
        const int n = blockIdx.x - VT_BLOCKS;           // token id, 0..NTOT-1

        if (tid < 64) {                                  // one sincos per distinct angle
            float th = theta[(size_t)n * D_ + tid];      // theta[d+64] == theta[d]
            __sincosf(th, &sn_[tid], &cs_[tid]);
        }
        __syncthreads();

        // ---- q-rope: 256 threads = 32 h x 8 granules; pre-scaled; -> o_out slots ----
        {
            const int h = tid >> 3, g = tid & 7, d0 = g * 8;
            const float* qp = q + ((size_t)n * H_ + h) * D_;
            alignas(16) float ql[8], qu[8];
            *(float4*)&ql[0] = *(const float4*)(qp + d0);
            *(float4*)&ql[4] = *(const float4*)(qp + d0 + 4);
            *(float4*)&qu[0] = *(const float4*)(qp + d0 + 64);
            *(float4*)&qu[4] = *(const float4*)(qp + d0 + 68);
            alignas(16) unsigned short ol[8], ou[8];
#pragma unroll
            for (int j = 0; j < 8; ++j) {
                float c = cs_[d0 + j], s = sn_[d0 + j];
                ol[j] = f2bf((ql[j] * c - qu[j] * s) * QSCALE_);
                ou[j] = f2bf((qu[j] * c + ql[j] * s) * QSCALE_);
            }
            unsigned short* outp = (unsigned short*)(o_out + ((size_t)n * H_ + h) * D_);
            *(int4v*)(outp + d0)      = *(const int4v*)ol;
            *(int4v*)(outp + d0 + 64) = *(const int4v*)ou;
        }

        // ---- k-rope: threads 0..63 = 8 hk x 8 granules; granule-swizzle baked ----
        if (tid < 64) {
            const int hk = tid >> 3, g = tid & 7, d0 = g * 8;
            const float* kp = k + ((size_t)n * HKV_ + hk) * D_;
            alignas(16) float kl[8], ku[8];
            *(float4*)&kl[0] = *(const float4*)(kp + d0);
            *(float4*)&kl[4] = *(const float4*)(kp + d0 + 4);
            *(float4*)&ku[0] = *(const float4*)(kp + d0 + 64);
            *(float4*)&ku[4] = *(const float4*)(kp + d0 + 68);
            alignas(16) unsigned short ol[8], ou[8];
#pragma unroll
            for (int j = 0; j < 8; ++j) {
                float c = cs_[d0 + j], s = sn_[d0 + j];
                ol[j] = f2bf(kl[j] * c - ku[j] * s);
                ou[j] = f2bf(ku[j] * c + kl[j] * s);
            }
            unsigned short* outp = kr + ((size_t)n * HKV_ + hk) * D_;
            const int swz = g ^ (n & 15);          // baked granule swizzle (key&15 == n&15)
            *(int4v*)(outp + swz * 8)       = *(const int4v*)ol;
            *(int4v*)(outp + (swz ^ 8) * 8) = *(const int4v*)ou;
        }
    }
}

// ---------------- flash attention (8-wave blocks, KT=32, XCD-clustered KV) ----------------
// 512 threads = 8 waves; wave w owns ONE 16-row q-sub-block (rows qbase+16w..+15).
// Same 128-row tile / LDS / swizzles as R11, but waves/CU ceiling rises 16 -> 24
// (launch_bounds(512,6): VGPR cap 85 = R11's measured 84, no-spill by construction).
// R11 was latency-bound at 23% occupancy with all pipes <40% — more co-resident
// waves is the lever. LDS reads per MFMA double (no dual-sub-block sharing) but the
// LDS pipe was ~25% busy — not binding.
// blockIdx.x = (h&3)*32 + b*8 + hk -> x%8 = hk: all 32 blocks sharing one (b,hk) KV
// segment land on ONE XCD's L2. Q read pre-roped/pre-scaled bf16 from o_out slots.
__global__ __launch_bounds__(512, 6)
void flash_kernel(const unsigned short* __restrict__ kr,
                  const unsigned short* __restrict__ vt,
                  float* o_out,
                  float* __restrict__ l_out) {
    __shared__ unsigned short Ks[2][KT_][D_];   // [buf][key][d]   8 KB/buf
    __shared__ unsigned short Vs[2][D_][KT_];   // [buf][d][key]   8 KB/buf

    const int tid  = threadIdx.x;
    const int wave = tid >> 6;                  // 0..7
    const int lane = tid & 63;
    const int l16  = lane & 15;
    const int quad = lane >> 4;

    const int x  = blockIdx.x;                  // x = (h&3)*32 + b*8 + hk
    const int hk = x & 7;
    const int b  = (x >> 3) & 3;
    const int h  = hk * 4 + (x >> 5);
    const int qt = (S_/QTB_ - 1) - blockIdx.y;  // heavy tiles first
    const int qbase = qt * QTB_;
    const int wq   = qbase + wave * 16;         // this wave's rows [wq, wq+16)
    const int qrow = wq + l16;

    // ---- Q B-fragments: pre-roped, pre-scaled bf16 from o_out slot (4x 16B loads) ----
    bf16x8 qfrag[4];
    {
        const int n = b * S_ + qrow;
        const unsigned short* qp = (const unsigned short*)(o_out + ((size_t)n * H_ + h) * D_);
#pragma unroll
        for (int c = 0; c < 4; ++c)
            qfrag[c] = *(const bf16x8*)(qp + c * 32 + quad * 8);
    }

    f32x4 acc[8];   // O^T: lane holds d = dt*16 + quad*4 + r, col = qrow
#pragma unroll
    for (int dt = 0; dt < 8; ++dt) acc[dt] = (f32x4){0.f, 0.f, 0.f, 0.f};
    float m_st = -1e30f, l_st = 0.f;   // running max (row-uniform) / per-LANE partial sum

    const unsigned short* kseg = kr + ((size_t)b * S_ * HKV_ + hk) * D_;
    const unsigned short* vseg = vt + ((size_t)(b * HKV_ + hk)) * D_ * S_;

    // ---- DMA lane addressing: 512 lanes stage the whole tile, 1 K + 1 V dma each ----
    const int krow = tid >> 4;                  // 0..31
    const int kcol = (tid & 15) * 8;
    const int vrow = tid >> 2;                  // 0..127
    const int vcol = (tid & 3) * 8;

#define STAGE(BUF, K0)                                                              \
    do {                                                                            \
        lds_dma16(kseg + (size_t)((K0) + krow) * (HKV_*D_) + kcol,                  \
                  &Ks[BUF][wave * 4][0]);                                           \
        lds_dma16(vseg + (size_t)vrow * S_ + (K0) + vcol,                           \
                  &Vs[BUF][wave * 16][0]);                                          \
    } while (0)

    // V read offsets: loop-invariant (row bits 1..3 == l16 bits 1..3; dt*16 is 16-aligned)
    const int voA = (quad ^ ((l16 >> 1) & 7)) * 4;    // keys 4q..4q+3   (pi: k'=8q..8q+3)
    const int voB = voA ^ 16;                         // keys 16+4q..+3  (pi: k'=8q+4..8q+7)

    const int n_kt = 4 * (qt + 1);
    STAGE(0, 0);

    for (int kt = 0; kt < n_kt; ++kt) {
        const int k0 = kt * KT_;
        const int buf = kt & 1;
        __syncthreads();                    // buf ready; other buf fully consumed
        if (kt + 1 < n_kt) STAGE(1 - buf, k0 + KT_);

        // active 16-key chunks for this wave (wave-uniform)
        const int dd = wq + 15 - k0;
        int nact = dd < 0 ? 0 : (dd >> 4) + 1;
        if (nact > 2) nact = 2;

        if (nact > 0) {
            // ---- S^T = K . Q^T ----
            f32x4 sc[2];
            __builtin_amdgcn_s_setprio(1);
#pragma unroll
            for (int kc = 0; kc < 2; ++kc) {
                if (kc < nact) {
                    f32x4 c = (f32x4){0.f, 0.f, 0.f, 0.f};
#pragma unroll
                    for (int cc = 0; cc < 4; ++cc) {
                        bf16x8 kf = *(const bf16x8*)&Ks[buf][kc * 16 + l16][((cc * 4 + quad) ^ l16) * 8];
                        c = __builtin_amdgcn_mfma_f32_16x16x32_bf16(kf, qfrag[cc], c, 0, 0, 0);
                    }
                    sc[kc] = c;
                }
            }
            __builtin_amdgcn_s_setprio(0);

            // ---- mask (only on edge tiles) ----
            float s[8];
            if (wq >= k0 + KT_ - 1) {       // fully below diagonal: no mask, nact==2
#pragma unroll
                for (int kc = 0; kc < 2; ++kc)
#pragma unroll
                    for (int r = 0; r < 4; ++r) s[kc * 4 + r] = sc[kc][r];
            } else {
#pragma unroll
                for (int kc = 0; kc < 2; ++kc)
#pragma unroll
                    for (int r = 0; r < 4; ++r) {
                        const int key = k0 + kc * 16 + quad * 4 + r;
                        s[kc * 4 + r] = (kc < nact && key <= qrow) ? sc[kc][r] : -1e30f;
                    }
            }

            // ---- row max (v_max3) + defer-max rescale (rare) ----
            float t0 = max3_(s[0], s[1], s[2]);
            float t1 = max3_(s[3], s[4], s[5]);
            float t2 = max3_(s[6], s[7], t0);
            float tmax = fmaxf(t1, t2);
            if (!__all(tmax <= m_st + DEFER_)) {
                float rmax = fmaxf(tmax, __shfl_xor(tmax, 16));
                rmax = fmaxf(rmax, __shfl_xor(rmax, 32));
                float mnew  = fmaxf(m_st, rmax);
                float alpha = exp2_(m_st - mnew);
                m_st = mnew;
                l_st *= alpha;
#pragma unroll
                for (int dt = 0; dt < 8; ++dt) {
                    acc[dt][0] *= alpha; acc[dt][1] *= alpha;
                    acc[dt][2] *= alpha; acc[dt][3] *= alpha;
                }
            }

            // ---- P = 2^(s - m), pack via v_cvt_pk_bf16_f32; l as per-lane partial ----
            float p[8];
#pragma unroll
            for (int i = 0; i < 8; ++i) p[i] = exp2_(s[i] - m_st);
            union { unsigned int u[4]; bf16x8 v; } pb;
            pb.u[0] = cvtpk_bf16(p[0], p[1]);
            pb.u[1] = cvtpk_bf16(p[2], p[3]);
            pb.u[2] = cvtpk_bf16(p[4], p[5]);
            pb.u[3] = cvtpk_bf16(p[6], p[7]);
            l_st += ((p[0] + p[1]) + (p[2] + p[3])) + ((p[4] + p[5]) + (p[6] + p[7]));

            // ---- O^T += V^T . P^T : one MFMA per dt (keys permuted by pi) ----
            __builtin_amdgcn_s_setprio(1);
#pragma unroll
            for (int dt = 0; dt < 8; ++dt) {
                const unsigned short* vrp = &Vs[buf][dt * 16 + l16][0];
                bf16x4 va = *(const bf16x4*)(vrp + voA);
                bf16x4 vb = *(const bf16x4*)(vrp + voB);
                bf16x8 vf8 = __builtin_shufflevector(va, vb, 0, 1, 2, 3, 4, 5, 6, 7);
                acc[dt] = __builtin_amdgcn_mfma_f32_16x16x32_bf16(vf8, pb.v, acc[dt], 0, 0, 0);
            }
            __builtin_amdgcn_s_setprio(0);
        }
    }

    // ---- epilogue: reduce per-lane l partials across quads once, store ----
    {
        float l2 = l_st + __shfl_xor(l_st, 16);
        float lf = l2 + __shfl_xor(l2, 32);
        const float inv = 1.0f / lf;
        const int n = b * S_ + qrow;
        float* op = o_out + ((size_t)n * H_ + h) * D_;
#pragma unroll
        for (int dt = 0; dt < 8; ++dt) {
            float4 o4 = {acc[dt][0] * inv, acc[dt][1] * inv, acc[dt][2] * inv, acc[dt][3] * inv};
            *(float4*)(op + dt * 16 + quad * 4) = o4;
        }
        if (quad == 0)
            l_out[(size_t)n * H_ + h] = m_st * LN2_ + __logf(lf);
    }
}

extern "C" void kernel_launch(void* const* d_in, const int* in_sizes, int n_in,
                              void* d_out, int out_size, void* d_ws, size_t ws_size,
                              hipStream_t stream) {
    const float* q     = (const float*)d_in[0];
    const float* k     = (const float*)d_in[1];
    const float* v     = (const float*)d_in[2];
    const float* theta = (const float*)d_in[3];
    // d_in[4] (mask) is exactly per-segment causal; applied structurally.

    float* o_out = (float*)d_out;
    float* l_out = o_out + (size_t)NTOT * H_ * D_;

    unsigned short* kr = (unsigned short*)d_ws;                 // N*HKV*D bf16 (granule-swizzled)
    unsigned short* vt = kr + (size_t)NTOT * HKV_ * D_;         // B*HKV*D*S bf16 (granule-swizzled)

    // fused prep: vt [0,512) | per-token rope (q->o_out slots, k->kr) [512, 512+NTOT)
    prep_kernel<<<VT_BLOCKS + NTOT, 256, 0, stream>>>(v, vt, k, theta, kr, q, o_out);

    dim3 grid(B_ * H_, S_ / QTB_);   // x = (h&3)*32 + b*8 + hk (XCD-clustered KV), y heavy-first
    flash_kernel<<<grid, 512, 0, stream>>>(kr, vt, o_out, l_out);
}

// Round 15
// 209.118 us; speedup vs baseline: 1.4216x; 1.4216x over previous
//
#include <hip/hip_runtime.h>

#define B_    4
#define S_    1024
#define H_    32
#define HKV_  8
#define D_    128
#define NTOT  (B_*S_)
#define QTB_  64       // q rows per block (4 waves x 16 rows, single sub-block per wave)
#define KT_   32

// 1/sqrt(128) * log2(e): scores computed directly in log2 domain
#define QSCALE_ (0.08838834764831845f * 1.4426950408889634f)
#define LN2_    0.6931471805599453f
#define DEFER_  11.5f   // defer-max threshold in log2 units (~e^8)

typedef __attribute__((ext_vector_type(8))) short bf16x8;
typedef __attribute__((ext_vector_type(4))) short bf16x4;
typedef __attribute__((ext_vector_type(4))) float f32x4;
typedef __attribute__((ext_vector_type(4))) int   int4v;

__device__ __forceinline__ unsigned short f2bf(float f) {
    unsigned int u = __float_as_uint(f);
    u += 0x7FFFu + ((u >> 16) & 1u);   // round-to-nearest-even
    return (unsigned short)(u >> 16);
}
__device__ __forceinline__ unsigned int pack2bf(float a, float b) {
    return (unsigned int)f2bf(a) | ((unsigned int)f2bf(b) << 16);
}
__device__ __forceinline__ unsigned int cvtpk_bf16(float a, float b) {
    unsigned int r;
    asm("v_cvt_pk_bf16_f32 %0, %1, %2" : "=v"(r) : "v"(a), "v"(b));
    return r;   // lo = bf16(a), hi = bf16(b), RNE
}
__device__ __forceinline__ float exp2_(float x) {
    float r; asm("v_exp_f32 %0, %1" : "=v"(r) : "v"(x)); return r;
}
__device__ __forceinline__ float max3_(float a, float b, float c) {
    float r; asm("v_max3_f32 %0, %1, %2, %3" : "=v"(r) : "v"(a), "v"(b), "v"(c)); return r;
}
// async global->LDS DMA, 16B/lane; lds base must be wave-uniform, lane l lands at base + l*16
__device__ __forceinline__ void lds_dma16(const void* g, void* l) {
    __builtin_amdgcn_global_load_lds(
        (const __attribute__((address_space(1))) unsigned int*)g,
        (__attribute__((address_space(3))) unsigned int*)l, 16, 0, 0);
}

// ---------------- fused prep ----------------
// blocks [0,512):        V cast+transpose -> vt (bank-swizzle BAKED)
// blocks [512,512+4096): per-token RoPE: sincos ONCE into LDS, then q-rope (32 h,
//                        pre-scaled, -> first 256B of o_out slots) and k-rope
//                        (8 hk, granule-swizzle BAKED -> kr).
#define VT_BLOCKS (B_ * HKV_ * (S_ / 64))   // 512
__global__ void prep_kernel(const float* __restrict__ v,
                            unsigned short* __restrict__ vt,
                            const float* __restrict__ k,
                            const float* __restrict__ theta,
                            unsigned short* __restrict__ kr,
                            const float* __restrict__ q,
                            float* __restrict__ o_out) {
    __shared__ unsigned int T[64][64];      // vt branch: [s][d-pair] swizzled staging
    __shared__ float cs_[64], sn_[64];      // rope branch: per-token sincos table
    const int tid = threadIdx.x;

    if (blockIdx.x < VT_BLOCKS) {
        int blk = blockIdx.x;               // B*HKV*(S/64) = 512 blocks
        int s0  = (blk & (S_/64 - 1)) * 64;
        int hk  = (blk >> 4) & (HKV_ - 1);
        int b   = blk >> 7;

#pragma unroll
        for (int i = 0; i < 8; ++i) {
            int u  = tid + 256 * i;
            int s  = u >> 5;             // 0..63
            int G  = u & 31;             // d granule (4 floats)
            float4 val = *(const float4*)(v + (((size_t)(b * S_ + s0 + s)) * HKV_ + hk) * D_ + G * 4);
            unsigned int* p = &T[s][(G ^ (s & 31)) << 1];
            p[0] = pack2bf(val.x, val.y);
            p[1] = pack2bf(val.z, val.w);
        }
        __syncthreads();
#pragma unroll
        for (int i = 0; i < 4; ++i) {
            int u = tid + 256 * i;
            int d = u >> 3;              // 0..127
            int g = u & 7;               // s granule of 8 keys within the 64-key block
            int G = d >> 2;
            int half = (d >> 1) & 1;
            int hi   = (d & 1) * 16;
            const int hswap = ((d >> 1) & 1) * 4;      // swap 8B halves iff s&1
            alignas(16) unsigned short tmp[8];
#pragma unroll
            for (int j = 0; j < 8; ++j) {
                int s = g * 8 + j;
                unsigned int w = T[s][(((G ^ (s & 31)) << 1)) + half];
                tmp[j ^ hswap] = (unsigned short)(w >> hi);
            }
            const int pos = (g >> 2) * 32 + (((g & 3) ^ ((d >> 2) & 3)) * 8);
            *(int4v*)(vt + (((size_t)(b * HKV_ + hk)) * D_ + d) * S_ + s0 + pos) = *(const int4v*)tmp;
        }
    } else {
        const int n = blockIdx.x - VT_BLOCKS;           // token id, 0..NTOT-1

        if (tid < 64) {                                  // one sincos per distinct angle
            float th = theta[(size_t)n * D_ + tid];      // theta[d+64] == theta[d]
            __sincosf(th, &sn_[tid], &cs_[tid]);
        }
        __syncthreads();

        // ---- q-rope: 256 threads = 32 h x 8 granules; pre-scaled; -> o_out slots ----
        {
            const int h = tid >> 3, g = tid & 7, d0 = g * 8;
            const float* qp = q + ((size_t)n * H_ + h) * D_;
            alignas(16) float ql[8], qu[8];
            *(float4*)&ql[0] = *(const float4*)(qp + d0);
            *(float4*)&ql[4] = *(const float4*)(qp + d0 + 4);
            *(float4*)&qu[0] = *(const float4*)(qp + d0 + 64);
            *(float4*)&qu[4] = *(const float4*)(qp + d0 + 68);
            alignas(16) unsigned short ol[8], ou[8];
#pragma unroll
            for (int j = 0; j < 8; ++j) {
                float c = cs_[d0 + j], s = sn_[d0 + j];
                ol[j] = f2bf((ql[j] * c - qu[j] * s) * QSCALE_);
                ou[j] = f2bf((qu[j] * c + ql[j] * s) * QSCALE_);
            }
            unsigned short* outp = (unsigned short*)(o_out + ((size_t)n * H_ + h) * D_);
            *(int4v*)(outp + d0)      = *(const int4v*)ol;
            *(int4v*)(outp + d0 + 64) = *(const int4v*)ou;
        }

        // ---- k-rope: threads 0..63 = 8 hk x 8 granules; granule-swizzle baked ----
        if (tid < 64) {
            const int hk = tid >> 3, g = tid & 7, d0 = g * 8;
            const float* kp = k + ((size_t)n * HKV_ + hk) * D_;
            alignas(16) float kl[8], ku[8];
            *(float4*)&kl[0] = *(const float4*)(kp + d0);
            *(float4*)&kl[4] = *(const float4*)(kp + d0 + 4);
            *(float4*)&ku[0] = *(const float4*)(kp + d0 + 64);
            *(float4*)&ku[4] = *(const float4*)(kp + d0 + 68);
            alignas(16) unsigned short ol[8], ou[8];
#pragma unroll
            for (int j = 0; j < 8; ++j) {
                float c = cs_[d0 + j], s = sn_[d0 + j];
                ol[j] = f2bf(kl[j] * c - ku[j] * s);
                ou[j] = f2bf(ku[j] * c + kl[j] * s);
            }
            unsigned short* outp = kr + ((size_t)n * HKV_ + hk) * D_;
            const int swz = g ^ (n & 15);          // baked granule swizzle (key&15 == n&15)
            *(int4v*)(outp + swz * 8)       = *(const int4v*)ol;
            *(int4v*)(outp + (swz ^ 8) * 8) = *(const int4v*)ou;
        }
    }
}

// ---------------- flash attention (single-sub-block waves, QTB=64, XCD-clustered KV) ----------------
// R11 was register-bound: 2-sub-block state (64 AGPR acc + 32 VGPR qfrag + addressing
// ~ 150 unified regs) -> ~3 waves/SIMD, 23% occupancy, all pipes <40%. This version
// halves per-wave state (one 16-row sub-block per wave: 32 acc + 16 qfrag) -> ~5-6
// waves/SIMD, and QTB=64 doubles the grid (2048 blocks, 8/CU schedulable) so dynamic
// block refill replaces the all-resident-then-decay tail. LDS/KT/swizzles/STAGE are
// R11's proven ones; LDS-read per MFMA doubles (pipe had ~2x headroom).
// blockIdx.x = (h&3)*32 + b*8 + hk -> x%8 = hk: all blocks sharing one (b,hk) KV
// segment land on ONE XCD's L2. Q read pre-roped/pre-scaled bf16 from o_out slots.
__global__ __launch_bounds__(256, 4)
void flash_kernel(const unsigned short* __restrict__ kr,
                  const unsigned short* __restrict__ vt,
                  float* o_out,
                  float* __restrict__ l_out) {
    __shared__ unsigned short Ks[2][KT_][D_];   // [buf][key][d]   8 KB/buf
    __shared__ unsigned short Vs[2][D_][KT_];   // [buf][d][key]   8 KB/buf

    const int tid  = threadIdx.x;
    const int wave = tid >> 6;                  // 0..3
    const int lane = tid & 63;
    const int l16  = lane & 15;
    const int quad = lane >> 4;

    const int x  = blockIdx.x;                  // x = (h&3)*32 + b*8 + hk
    const int hk = x & 7;
    const int b  = (x >> 3) & 3;
    const int h  = hk * 4 + (x >> 5);
    const int qt = (S_/QTB_ - 1) - blockIdx.y;  // heavy tiles first
    const int qbase = qt * QTB_;
    const int wq   = qbase + wave * 16;         // this wave's rows [wq, wq+16)
    const int qrow = wq + l16;

    // ---- Q B-fragments: pre-roped, pre-scaled bf16 from o_out slot (4x 16B loads) ----
    bf16x8 qfrag[4];
    {
        const int n = b * S_ + qrow;
        const unsigned short* qp = (const unsigned short*)(o_out + ((size_t)n * H_ + h) * D_);
#pragma unroll
        for (int c = 0; c < 4; ++c)
            qfrag[c] = *(const bf16x8*)(qp + c * 32 + quad * 8);
    }

    f32x4 acc[8];   // O^T: lane holds d = dt*16 + quad*4 + r, col = qrow
#pragma unroll
    for (int dt = 0; dt < 8; ++dt) acc[dt] = (f32x4){0.f, 0.f, 0.f, 0.f};
    float m_st = -1e30f, l_st = 0.f;   // running max (row-uniform) / per-LANE partial sum

    const unsigned short* kseg = kr + ((size_t)b * S_ * HKV_ + hk) * D_;
    const unsigned short* vseg = vt + ((size_t)(b * HKV_ + hk)) * D_ * S_;

    // ---- DMA lane addressing (4 waves stage the 16KB tile, 4 dma16/thread) ----
    const int krow0 = wave * 8 + (lane >> 4);          // K rows: wave w -> [8w, 8w+8)
    const int kcol  = (lane & 15) * 8;
    const int vrow0 = wave * 32 + (lane >> 2);         // V rows: wave w -> [32w, 32w+32)
    const int vcol  = (lane & 3) * 8;

#define STAGE(BUF, K0)                                                              \
    do {                                                                            \
        lds_dma16(kseg + (size_t)((K0) + krow0) * (HKV_*D_) + kcol,                 \
                  &Ks[BUF][wave * 8][0]);                                           \
        lds_dma16(kseg + (size_t)((K0) + krow0 + 4) * (HKV_*D_) + kcol,             \
                  &Ks[BUF][wave * 8 + 4][0]);                                       \
        lds_dma16(vseg + (size_t)vrow0 * S_ + (K0) + vcol,                          \
                  &Vs[BUF][wave * 32][0]);                                          \
        lds_dma16(vseg + (size_t)(vrow0 + 16) * S_ + (K0) + vcol,                   \
                  &Vs[BUF][wave * 32 + 16][0]);                                     \
    } while (0)

    // V read offsets: loop-invariant (row bits 1..3 == l16 bits 1..3; dt*16 is 16-aligned)
    const int voA = (quad ^ ((l16 >> 1) & 7)) * 4;    // keys 4q..4q+3   (pi: k'=8q..8q+3)
    const int voB = voA ^ 16;                         // keys 16+4q..+3  (pi: k'=8q+4..8q+7)

    const int n_kt = 2 * (qt + 1);                    // >= 2
    STAGE(0, 0);

    for (int kt = 0; kt < n_kt; ++kt) {
        const int k0 = kt * KT_;
        const int buf = kt & 1;
        __syncthreads();                    // buf ready; other buf fully consumed
        if (kt + 1 < n_kt) STAGE(1 - buf, k0 + KT_);

        // active 16-key chunks for this wave (wave-uniform)
        const int dd = wq + 15 - k0;
        int nact = dd < 0 ? 0 : (dd >> 4) + 1;
        if (nact > 2) nact = 2;

        if (nact > 0) {
            // ---- S^T = K . Q^T ----
            f32x4 sc[2];
            __builtin_amdgcn_s_setprio(1);
#pragma unroll
            for (int kc = 0; kc < 2; ++kc) {
                if (kc < nact) {
                    f32x4 c = (f32x4){0.f, 0.f, 0.f, 0.f};
#pragma unroll
                    for (int cc = 0; cc < 4; ++cc) {
                        bf16x8 kf = *(const bf16x8*)&Ks[buf][kc * 16 + l16][((cc * 4 + quad) ^ l16) * 8];
                        c = __builtin_amdgcn_mfma_f32_16x16x32_bf16(kf, qfrag[cc], c, 0, 0, 0);
                    }
                    sc[kc] = c;
                }
            }
            __builtin_amdgcn_s_setprio(0);

            // ---- mask (only on edge tiles) ----
            float s[8];
            if (wq >= k0 + KT_ - 1) {       // fully below diagonal: no mask, nact==2
#pragma unroll
                for (int kc = 0; kc < 2; ++kc)
#pragma unroll
                    for (int r = 0; r < 4; ++r) s[kc * 4 + r] = sc[kc][r];
            } else {
#pragma unroll
                for (int kc = 0; kc < 2; ++kc)
#pragma unroll
                    for (int r = 0; r < 4; ++r) {
                        const int key = k0 + kc * 16 + quad * 4 + r;
                        s[kc * 4 + r] = (kc < nact && key <= qrow) ? sc[kc][r] : -1e30f;
                    }
            }

            // ---- row max (v_max3) + defer-max rescale (rare) ----
            float t0 = max3_(s[0], s[1], s[2]);
            float t1 = max3_(s[3], s[4], s[5]);
            float t2 = max3_(s[6], s[7], t0);
            float tmax = fmaxf(t1, t2);
            if (!__all(tmax <= m_st + DEFER_)) {
                float rmax = fmaxf(tmax, __shfl_xor(tmax, 16));
                rmax = fmaxf(rmax, __shfl_xor(rmax, 32));
                float mnew  = fmaxf(m_st, rmax);
                float alpha = exp2_(m_st - mnew);
                m_st = mnew;
                l_st *= alpha;
#pragma unroll
                for (int dt = 0; dt < 8; ++dt) {
                    acc[dt][0] *= alpha; acc[dt][1] *= alpha;
                    acc[dt][2] *= alpha; acc[dt][3] *= alpha;
                }
            }

            // ---- P = 2^(s - m), pack via v_cvt_pk_bf16_f32; l as per-lane partial ----
            float p[8];
#pragma unroll
            for (int i = 0; i < 8; ++i) p[i] = exp2_(s[i] - m_st);
            union { unsigned int u[4]; bf16x8 v; } pb;
            pb.u[0] = cvtpk_bf16(p[0], p[1]);
            pb.u[1] = cvtpk_bf16(p[2], p[3]);
            pb.u[2] = cvtpk_bf16(p[4], p[5]);
            pb.u[3] = cvtpk_bf16(p[6], p[7]);
            l_st += ((p[0] + p[1]) + (p[2] + p[3])) + ((p[4] + p[5]) + (p[6] + p[7]));

            // ---- O^T += V^T . P^T : one MFMA per dt (keys permuted by pi) ----
            __builtin_amdgcn_s_setprio(1);
#pragma unroll
            for (int dt = 0; dt < 8; ++dt) {
                const unsigned short* vrp = &Vs[buf][dt * 16 + l16][0];
                bf16x4 va = *(const bf16x4*)(vrp + voA);
                bf16x4 vb = *(const bf16x4*)(vrp + voB);
                bf16x8 vf8 = __builtin_shufflevector(va, vb, 0, 1, 2, 3, 4, 5, 6, 7);
                acc[dt] = __builtin_amdgcn_mfma_f32_16x16x32_bf16(vf8, pb.v, acc[dt], 0, 0, 0);
            }
            __builtin_amdgcn_s_setprio(0);
        }
    }

    // ---- epilogue: reduce per-lane l partials across quads once, store ----
    {
        float l2 = l_st + __shfl_xor(l_st, 16);
        float lf = l2 + __shfl_xor(l2, 32);
        const float inv = 1.0f / lf;
        const int n = b * S_ + qrow;
        float* op = o_out + ((size_t)n * H_ + h) * D_;
#pragma unroll
        for (int dt = 0; dt < 8; ++dt) {
            float4 o4 = {acc[dt][0] * inv, acc[dt][1] * inv, acc[dt][2] * inv, acc[dt][3] * inv};
            *(float4*)(op + dt * 16 + quad * 4) = o4;
        }
        if (quad == 0)
            l_out[(size_t)n * H_ + h] = m_st * LN2_ + __logf(lf);
    }
}

extern "C" void kernel_launch(void* const* d_in, const int* in_sizes, int n_in,
                              void* d_out, int out_size, void* d_ws, size_t ws_size,
                              hipStream_t stream) {
    const float* q     = (const float*)d_in[0];
    const float* k     = (const float*)d_in[1];
    const float* v     = (const float*)d_in[2];
    const float* theta = (const float*)d_in[3];
    // d_in[4] (mask) is exactly per-segment causal; applied structurally.

    float* o_out = (float*)d_out;
    float* l_out = o_out + (size_t)NTOT * H_ * D_;

    unsigned short* kr = (unsigned short*)d_ws;                 // N*HKV*D bf16 (granule-swizzled)
    unsigned short* vt = kr + (size_t)NTOT * HKV_ * D_;         // B*HKV*D*S bf16 (granule-swizzled)

    // fused prep: vt [0,512) | per-token rope (q->o_out slots, k->kr) [512, 512+NTOT)
    prep_kernel<<<VT_BLOCKS + NTOT, 256, 0, stream>>>(v, vt, k, theta, kr, q, o_out);

    dim3 grid(B_ * H_, S_ / QTB_);   // x = (h&3)*32 + b*8 + hk (XCD-clustered KV), y heavy-first
    flash_kernel<<<grid, 256, 0, stream>>>(kr, vt, o_out, l_out);
}